// Round 10
// baseline (124.949 us; speedup 1.0000x reference)
//
#include <hip/hip_runtime.h>

// FixedActionDecoder: sims = (X/||x||) @ (A/||a||cols); segment-max over
// ACTION_INDEX=[0,0,0,0,1,1,1,1,1,2,3]; argmax; one-hot.
// Row-norm of X is argmax-invariant -> skipped.
//
// r10 = r9's proven compute core + r5's DMA staging, de-confounded:
//  - decode: per wave, 128-row tiles, TWO half-phase buffers (16 KB each,
//    linear) filled by global_load_lds (async DMA). Next half's 16 DMAs are
//    issued BEFORE computing the current half -> HBM latency hides under
//    compute within the wave (r9 relied only on 2-wave/SIMD overlap).
//    vmcnt ledger (in-order retirement): phase0 wait vmcnt(16) [exact on
//    first iter, <=2-op overwait steady]; phase1 pf?vmcnt(16):vmcnt(0).
//    Epilogue stores/repair-loads sit between the h0- and h1-ISSUEs, so
//    any compiler placement only causes safe overwaits.
//  - XOR source-swizzle fsrc = (lane&7)^(lane>>3), read slot kk^(lane&7)
//    (rule 21: same involution both sides; conflict-free b128, r5-proven).
//  - W broadcast from LDS as d-major quads (r9-proven; r5's s_load-chain
//    W was its real cost, NOT the DMA).
//  - repair FUSED as a cold divergent f64 branch (~1e3 rows of 1e6):
//    repair kernel + g_bits deleted.
// r6 lesson: no register staging arrays (DMA bypasses VGPRs entirely).
// Numerics: f32 pass + gap<TAU -> f64 recompute (r1/r2-validated path).

#define NP 11
#define TAU 1e-3f

__device__ __align__(16) float g_W32[704];  // [(d>>2)*44 + p*4 + (d&3)]
__device__ double g_W64[704];               // [d*11 + p]

// Parallel prep (~2us): thread d owns row d of A; column norms via LDS.
__global__ void prep(const float* __restrict__ A) {
    __shared__ double sq[64][NP + 1];
    __shared__ double sc[NP];
    const int d = threadIdx.x;  // 0..63
    double a[NP];
    #pragma unroll
    for (int p = 0; p < NP; ++p) {
        a[p] = (double)A[d * NP + p];
        sq[d][p] = a[p] * a[p];
    }
    __syncthreads();
    if (d < NP) {
        double ss = 0.0;
        #pragma unroll
        for (int r = 0; r < 64; ++r) ss += sq[r][d];
        sc[d] = 1.0 / fmax(sqrt(ss), 1e-8);
    }
    __syncthreads();
    #pragma unroll
    for (int p = 0; p < NP; ++p) {
        double w = a[p] * sc[p];
        g_W64[d * NP + p] = w;
        g_W32[(d >> 2) * 44 + p * 4 + (d & 3)] = (float)w;  // d-major quad
    }
}

// One half-phase = 128 rows x 32 floats = 16 KB = 16 DMA instrs; each instr
// covers 8 rows x one full 128B line. LDS dest linear; source f pre-swizzled.
#define ISSUE(tbase, phase, ldsbuf)                                            \
    {                                                                          \
        _Pragma("unroll") for (int i = 0; i < 16; ++i) {                       \
            int r = (tbase) + i * 8 + hi3;                                     \
            if (r >= B) r = B - 1; /* tail clamp: dup read, never stored */    \
            const float4* src = X4 + (size_t)r * 16 + (phase) * 8 + fsrc;      \
            __builtin_amdgcn_global_load_lds(                                  \
                (const __attribute__((address_space(1))) void*)src,            \
                (__attribute__((address_space(3))) void*)((ldsbuf) + i * 64),  \
                16, 0, 0);                                                     \
        }                                                                      \
    }

// Per chunk: 2 swizzled lane b128 (X rows lane, lane+64) + 11 uniform b128
// (W quads) + 88 v_fma_f32. unroll 1: W never bulk-hoisted (r2 lesson).
#define COMPUTE(phase, bufp)                                                   \
    {                                                                          \
        _Pragma("unroll 1") for (int kk = 0; kk < 8; ++kk) {                   \
            const int sw = kk ^ s7;                                            \
            float4 x0 = (bufp)[lane * 8 + sw];                                 \
            float4 x1 = (bufp)[(lane + 64) * 8 + sw];                          \
            const float* wrow = &w_lds[((phase) * 8 + kk) * 44];               \
            _Pragma("unroll") for (int p = 0; p < NP; ++p) {                   \
                float4 wq = *reinterpret_cast<const float4*>(&wrow[p * 4]);    \
                float t0 = fmaf(x0.x, wq.x, acc0[p]);                          \
                t0 = fmaf(x0.y, wq.y, t0);                                     \
                t0 = fmaf(x0.z, wq.z, t0);                                     \
                acc0[p] = fmaf(x0.w, wq.w, t0);                                \
                float t1 = fmaf(x1.x, wq.x, acc1[p]);                          \
                t1 = fmaf(x1.y, wq.y, t1);                                     \
                t1 = fmaf(x1.z, wq.z, t1);                                     \
                acc1[p] = fmaf(x1.w, wq.w, t1);                                \
            }                                                                  \
        }                                                                      \
    }

__device__ __forceinline__ void argmax_gap(const float* s, int& idx, float& gap) {
    // Segment max per ACTION_INDEX = [0,0,0,0, 1,1,1,1,1, 2, 3]
    float m0 = fmaxf(fmaxf(s[0], s[1]), fmaxf(s[2], s[3]));
    float m1 = fmaxf(fmaxf(fmaxf(s[4], s[5]), s[6]), fmaxf(s[7], s[8]));
    float m2 = s[9], m3 = s[10];
    idx = 0; float best = m0;
    if (m1 > best) { best = m1; idx = 1; }
    if (m2 > best) { best = m2; idx = 2; }
    if (m3 > best) { best = m3; idx = 3; }
    float second = -3.4e38f;
    if (idx != 0) second = fmaxf(second, m0);
    if (idx != 1) second = fmaxf(second, m1);
    if (idx != 2) second = fmaxf(second, m2);
    if (idx != 3) second = fmaxf(second, m3);
    gap = best - second;
}

// Cold path: exact f64 recompute of one row (r1/r2-validated numerics).
__device__ int repair_row(const float* __restrict__ X, int row) {
    double s[NP];
    #pragma unroll
    for (int p = 0; p < NP; ++p) s[p] = 0.0;
    #pragma unroll 1
    for (int d = 0; d < 64; ++d) {
        double x = (double)X[(size_t)row * 64 + d];
        #pragma unroll
        for (int p = 0; p < NP; ++p)
            s[p] = fma(x, g_W64[d * NP + p], s[p]);
    }
    double m0 = fmax(fmax(s[0], s[1]), fmax(s[2], s[3]));
    double m1 = fmax(fmax(fmax(s[4], s[5]), s[6]), fmax(s[7], s[8]));
    double m2 = s[9], m3 = s[10];
    int idx = 0; double best = m0;
    if (m1 > best) { best = m1; idx = 1; }
    if (m2 > best) { best = m2; idx = 2; }
    if (m3 > best) { best = m3; idx = 3; }
    return idx;
}

__global__ __launch_bounds__(128) void decode(const float* __restrict__ X,
                                              float* __restrict__ out, int B) {
    // 2 waves x 2 half-phase buffers x 16 KB + W = 68352 B -> 2 blocks/CU.
    __shared__ float4 sbuf[2][2][1024];
    __shared__ float w_lds[704];

    const int tid = threadIdx.x;
    const int lane = tid & 63;
    const int wv = tid >> 6;
    const int s7 = lane & 7;
    const int hi3 = lane >> 3;
    const int fsrc = s7 ^ hi3;  // source-side swizzle (involution, rule 21)

    for (int t = tid; t < 176; t += 128)
        reinterpret_cast<float4*>(w_lds)[t] =
            reinterpret_cast<const float4*>(g_W32)[t];
    __syncthreads();  // only block-wide sync; everything after is per-wave

    float4* bufA = &sbuf[wv][0][0];
    float4* bufB = &sbuf[wv][1][0];
    const float4* X4 = reinterpret_cast<const float4*>(X);
    const int gwave = blockIdx.x * 2 + wv;
    const int stride = gridDim.x * 2 * 128;
    const int base0 = gwave * 128;
    if (base0 >= B) return;

    // Prologue: both half-buffers of the first tile in flight (32 DMAs).
    ISSUE(base0, 0, bufA);
    ISSUE(base0, 1, bufB);

    #pragma unroll 1
    for (int base = base0; base < B; base += stride) {
        const int next = base + stride;
        const bool pf = next < B;

        float acc0[NP], acc1[NP];
        #pragma unroll
        for (int p = 0; p < NP; ++p) { acc0[p] = 0.0f; acc1[p] = 0.0f; }

        // --- phase 0: h0 data is the 16 oldest ops; keep h1's 16 in flight.
        asm volatile("s_waitcnt vmcnt(16)" ::: "memory");
        __builtin_amdgcn_sched_barrier(0);
        COMPUTE(0, bufA);
        if (pf) ISSUE(next, 0, bufA);  // bufA reads completed above

        // --- phase 1: drain h1 (keep next.h0 in flight when prefetching).
        if (pf) {
            asm volatile("s_waitcnt vmcnt(16)" ::: "memory");
        } else {
            asm volatile("s_waitcnt vmcnt(0)" ::: "memory");
        }
        __builtin_amdgcn_sched_barrier(0);
        COMPUTE(1, bufB);

        // --- epilogue (between h0-ISSUE and h1-ISSUE: ledger-safe).
        int idx0, idx1; float gap0, gap1;
        argmax_gap(acc0, idx0, gap0);
        argmax_gap(acc1, idx1, gap1);

        const int r0 = base + lane, r1 = base + 64 + lane;
        const bool f0 = (gap0 < TAU) && (r0 < B);
        const bool f1 = (gap1 < TAU) && (r1 < B);
        if (__builtin_expect(__any(f0 || f1), 0)) {  // cold: ~1e3 of 1e6 rows
            if (f0) idx0 = repair_row(X, r0);
            if (f1) idx1 = repair_row(X, r1);
        }

        if (r0 < B) {
            float4 o;
            o.x = (idx0 == 0) ? 1.0f : 0.0f;
            o.y = (idx0 == 1) ? 1.0f : 0.0f;
            o.z = (idx0 == 2) ? 1.0f : 0.0f;
            o.w = (idx0 == 3) ? 1.0f : 0.0f;
            reinterpret_cast<float4*>(out)[r0] = o;
        }
        if (r1 < B) {
            float4 o;
            o.x = (idx1 == 0) ? 1.0f : 0.0f;
            o.y = (idx1 == 1) ? 1.0f : 0.0f;
            o.z = (idx1 == 2) ? 1.0f : 0.0f;
            o.w = (idx1 == 3) ? 1.0f : 0.0f;
            reinterpret_cast<float4*>(out)[r1] = o;
        }

        if (pf) ISSUE(next, 1, bufB);  // needed only at next iter's phase 1
    }
}

extern "C" void kernel_launch(void* const* d_in, const int* in_sizes, int n_in,
                              void* d_out, int out_size, void* d_ws, size_t ws_size,
                              hipStream_t stream) {
    const float* X = (const float*)d_in[0];
    const float* A = (const float*)d_in[1];
    float* out = (float*)d_out;
    const int B = in_sizes[0] / 64;

    hipLaunchKernelGGL(prep, dim3(1), dim3(64), 0, stream, A);
    hipLaunchKernelGGL(decode, dim3(512), dim3(128), 0, stream, X, out, B);
}

// Round 11
// 98.726 us; speedup vs baseline: 1.2656x; 1.2656x over previous
//
#include <hip/hip_runtime.h>

// FixedActionDecoder: sims = (X/||x||) @ (A/||a||cols); segment-max over
// ACTION_INDEX=[0,0,0,0,1,1,1,1,1,2,3]; argmax; one-hot.
// Row-norm of X is argmax-invariant -> skipped.
//
// r11 = r9 (best measured: 77.8us) + r10's correctness-proven fused repair:
//  - decode: r9 VERBATIM core. Half-row phases (8 lanes/row -> every staging
//    request covers a full 128B line), 128-row wave tiles, 2 rows/lane,
//    stride-36 LDS rows, W broadcast as d-major quads (11 uniform
//    ds_read_b128 per chunk), 4 blocks/CU = 8 waves/CU.
//  - repair FUSED as a cold divergent branch (~1e3 of 1e6 rows): f64
//    recompute when top-2 gap < TAU. Repair kernel + g_bits deleted
//    (saves ~6us kernel + ~2us launch gap + mask traffic).
//  - prep: parallel version (~2us).
// Lessons carried: r2 (no bulk-hoist of uniform tables -> unroll 1),
// r6 (no persistent reg staging arrays), r3 (device globals, never d_ws),
// r5/r10 (DMA global_load_lds abandoned: 1 wave/SIMD + stores-in-vmcnt-queue
// stall; plain staging + 8 waves/CU measured faster).
// Numerics: f32 pass + gap<TAU -> f64 recompute (r1/r2-validated; absmax 0
// in every passing round).

#define NP 11
#define TAU 1e-3f
#define LROW 36  // LDS row stride (dwords): 32 data + 4 pad (r4/r9-verified)

__device__ __align__(16) float g_W32[704];  // [(d>>2)*44 + p*4 + (d&3)]
__device__ double g_W64[704];               // [d*11 + p]

// Parallel prep (~2us): thread d owns row d of A; column norms via LDS.
__global__ void prep(const float* __restrict__ A) {
    __shared__ double sq[64][NP + 1];
    __shared__ double sc[NP];
    const int d = threadIdx.x;  // 0..63
    double a[NP];
    #pragma unroll
    for (int p = 0; p < NP; ++p) {
        a[p] = (double)A[d * NP + p];
        sq[d][p] = a[p] * a[p];
    }
    __syncthreads();
    if (d < NP) {
        double ss = 0.0;
        #pragma unroll
        for (int r = 0; r < 64; ++r) ss += sq[r][d];
        sc[d] = 1.0 / fmax(sqrt(ss), 1e-8);
    }
    __syncthreads();
    #pragma unroll
    for (int p = 0; p < NP; ++p) {
        double w = a[p] * sc[p];
        g_W64[d * NP + p] = w;
        g_W32[(d >> 2) * 44 + p * 4 + (d & 3)] = (float)w;  // d-major quad
    }
}

__device__ __forceinline__ void argmax_gap(const float* s, int& idx, float& gap) {
    // Segment max per ACTION_INDEX = [0,0,0,0, 1,1,1,1,1, 2, 3]
    float m0 = fmaxf(fmaxf(s[0], s[1]), fmaxf(s[2], s[3]));
    float m1 = fmaxf(fmaxf(fmaxf(s[4], s[5]), s[6]), fmaxf(s[7], s[8]));
    float m2 = s[9], m3 = s[10];
    idx = 0; float best = m0;
    if (m1 > best) { best = m1; idx = 1; }
    if (m2 > best) { best = m2; idx = 2; }
    if (m3 > best) { best = m3; idx = 3; }
    float second = -3.4e38f;
    if (idx != 0) second = fmaxf(second, m0);
    if (idx != 1) second = fmaxf(second, m1);
    if (idx != 2) second = fmaxf(second, m2);
    if (idx != 3) second = fmaxf(second, m3);
    gap = best - second;
}

// Cold path: exact f64 recompute of one row (r1/r2-validated numerics).
__device__ __noinline__ int repair_row(const float* __restrict__ X, int row) {
    double s[NP];
    #pragma unroll
    for (int p = 0; p < NP; ++p) s[p] = 0.0;
    #pragma unroll 1
    for (int d = 0; d < 64; ++d) {
        double x = (double)X[(size_t)row * 64 + d];
        #pragma unroll
        for (int p = 0; p < NP; ++p)
            s[p] = fma(x, g_W64[d * NP + p], s[p]);
    }
    double m0 = fmax(fmax(s[0], s[1]), fmax(s[2], s[3]));
    double m1 = fmax(fmax(fmax(s[4], s[5]), s[6]), fmax(s[7], s[8]));
    double m2 = s[9], m3 = s[10];
    int idx = 0; double best = m0;
    if (m1 > best) { best = m1; idx = 1; }
    if (m2 > best) { best = m2; idx = 2; }
    if (m3 > best) { best = m3; idx = 3; }
    return idx;
}

__global__ __launch_bounds__(128) void decode(const float* __restrict__ X,
                                              float* __restrict__ out, int B) {
    __shared__ float xbuf[2][128][LROW];  // 36864 B, wave-private halves
    __shared__ float w_lds[704];          // 2816 B; total 39680 -> 4 blk/CU

    const int tid = threadIdx.x;
    const int lane = tid & 63;
    const int wv = tid >> 6;
    float(*buf)[LROW] = xbuf[wv];

    // Copy W into LDS: 176 float4s over 128 threads.
    for (int t = tid; t < 176; t += 128)
        reinterpret_cast<float4*>(w_lds)[t] =
            reinterpret_cast<const float4*>(g_W32)[t];
    __syncthreads();  // only block-wide sync; rest is wave-private

    const float4* X4 = reinterpret_cast<const float4*>(X);
    const int gwave = blockIdx.x * 2 + wv;
    const int nwaves = gridDim.x * 2;

    #pragma unroll 1
    for (int base = gwave * 128; base < B; base += nwaves * 128) {
        float acc0[NP], acc1[NP];
        #pragma unroll
        for (int p = 0; p < NP; ++p) { acc0[p] = 0.0f; acc1[p] = 0.0f; }

        #pragma unroll
        for (int st = 0; st < 2; ++st) {  // d half: st*32 .. st*32+31
            // Stage 128 rows x 32 floats; instr i covers 8 FULL 128B lines
            // (8 lanes/row x 16 B contiguous).
            #pragma unroll
            for (int i = 0; i < 16; ++i) {
                int fid = i * 64 + lane;  // 0..1023
                int row = fid >> 3;       // 0..127
                int f = fid & 7;          // 0..7
                int r = base + row;
                if (r >= B) r = B - 1;    // tail clamp (dup read, harmless)
                float4 v = X4[(size_t)r * 16 + st * 8 + f];
                *reinterpret_cast<float4*>(&buf[row][f * 4]) = v;
            }
            __builtin_amdgcn_wave_barrier();  // wave-private buf: fence only

            // Per 4-d chunk: 2 lane b128 (X rows) + 11 uniform b128 (W
            // quads) + 88 v_fma_f32. unroll 1: W never bulk-hoisted (r2).
            #pragma unroll 1
            for (int kk = 0; kk < 8; ++kk) {
                const float* wrow = &w_lds[(st * 8 + kk) * 44];
                float4 x0 = *reinterpret_cast<const float4*>(&buf[lane][kk * 4]);
                float4 x1 = *reinterpret_cast<const float4*>(&buf[lane + 64][kk * 4]);
                #pragma unroll
                for (int p = 0; p < NP; ++p) {
                    float4 wq = *reinterpret_cast<const float4*>(&wrow[p * 4]);
                    float t0 = fmaf(x0.x, wq.x, acc0[p]);
                    t0 = fmaf(x0.y, wq.y, t0);
                    t0 = fmaf(x0.z, wq.z, t0);
                    acc0[p] = fmaf(x0.w, wq.w, t0);
                    float t1 = fmaf(x1.x, wq.x, acc1[p]);
                    t1 = fmaf(x1.y, wq.y, t1);
                    t1 = fmaf(x1.z, wq.z, t1);
                    acc1[p] = fmaf(x1.w, wq.w, t1);
                }
            }
            __builtin_amdgcn_wave_barrier();
        }

        int idx0, idx1; float gap0, gap1;
        argmax_gap(acc0, idx0, gap0);
        argmax_gap(acc1, idx1, gap1);

        const int r0 = base + lane, r1 = base + 64 + lane;
        const bool f0 = (gap0 < TAU) && (r0 < B);
        const bool f1 = (gap1 < TAU) && (r1 < B);
        if (__builtin_expect(__any(f0 || f1), 0)) {  // cold: ~1e3 of 1e6 rows
            if (f0) idx0 = repair_row(X, r0);
            if (f1) idx1 = repair_row(X, r1);
        }

        if (r0 < B) {
            float4 o;
            o.x = (idx0 == 0) ? 1.0f : 0.0f;
            o.y = (idx0 == 1) ? 1.0f : 0.0f;
            o.z = (idx0 == 2) ? 1.0f : 0.0f;
            o.w = (idx0 == 3) ? 1.0f : 0.0f;
            reinterpret_cast<float4*>(out)[r0] = o;
        }
        if (r1 < B) {
            float4 o;
            o.x = (idx1 == 0) ? 1.0f : 0.0f;
            o.y = (idx1 == 1) ? 1.0f : 0.0f;
            o.z = (idx1 == 2) ? 1.0f : 0.0f;
            o.w = (idx1 == 3) ? 1.0f : 0.0f;
            reinterpret_cast<float4*>(out)[r1] = o;
        }
    }
}

extern "C" void kernel_launch(void* const* d_in, const int* in_sizes, int n_in,
                              void* d_out, int out_size, void* d_ws, size_t ws_size,
                              hipStream_t stream) {
    const float* X = (const float*)d_in[0];
    const float* A = (const float*)d_in[1];
    float* out = (float*)d_out;
    const int B = in_sizes[0] / 64;

    hipLaunchKernelGGL(prep, dim3(1), dim3(64), 0, stream, A);
    hipLaunchKernelGGL(decode, dim3(1024), dim3(128), 0, stream, X, out, B);
}